// Round 5
// baseline (193.330 us; speedup 1.0000x reference)
//
#include <hip/hip_runtime.h>
#include <math.h>

#define BB 4
#define TT 1024
#define DD 512
#define HH 8
#define DHH 64

typedef short bf8_t __attribute__((ext_vector_type(8)));
typedef float f32x4 __attribute__((ext_vector_type(4)));

__device__ __forceinline__ float softplus_f(float z) {
    return fmaxf(z, 0.f) + log1pf(__expf(-fabsf(z)));
}

__device__ __forceinline__ unsigned short f2bf(float f) {
    union { float f; unsigned int u; } v; v.f = f;
    return (unsigned short)((v.u + 0x7FFFu + ((v.u >> 16) & 1u)) >> 16);
}

// ---------------------------------------------------------------------------
// K0a: cast x (f32 [4096][512]) -> bf16
// ---------------------------------------------------------------------------
__global__ __launch_bounds__(256) void cast_x_kernel(
    const float* __restrict__ x, unsigned short* __restrict__ xbf)
{
    int i = blockIdx.x * 256 + threadIdx.x;   // 8 elems per thread
    float4 a = *(const float4*)&x[(size_t)i * 8];
    float4 b = *(const float4*)&x[(size_t)i * 8 + 4];
    union { unsigned short u[8]; int4 v; } o;
    o.u[0] = f2bf(a.x); o.u[1] = f2bf(a.y); o.u[2] = f2bf(a.z); o.u[3] = f2bf(a.w);
    o.u[4] = f2bf(b.x); o.u[5] = f2bf(b.y); o.u[6] = f2bf(b.z); o.u[7] = f2bf(b.w);
    *(int4*)&xbf[(size_t)i * 8] = o.v;
}

// ---------------------------------------------------------------------------
// K0b: transpose+cast the 512x512 weights into W^T bf16 [n][k].
// z: 0=Wq 1=Wk 2=Wv (-> wt rows z*512..) 3=Wo (-> woT) 4=Ws (-> wt rows 1536..)
// ---------------------------------------------------------------------------
__global__ __launch_bounds__(256) void transpose_w_kernel(
    const float* __restrict__ Wq, const float* __restrict__ Wk,
    const float* __restrict__ Wv, const float* __restrict__ Wo,
    const float* __restrict__ Ws,
    unsigned short* __restrict__ wt, unsigned short* __restrict__ woT)
{
    __shared__ float tile[32][33];
    const int tid = threadIdx.x;
    const int z = blockIdx.z;
    if (z == 4) {                       // Ws [512][8] -> wt rows 1536..1543
        if (blockIdx.x != 0 || blockIdx.y != 0) return;
        #pragma unroll
        for (int i = 0; i < 16; ++i) {
            int idx = i * 256 + tid;    // = k*8 + n
            int k = idx >> 3, n = idx & 7;
            wt[(size_t)(1536 + n) * 512 + k] = f2bf(Ws[idx]);
        }
        return;
    }
    const float* W = (z == 0) ? Wq : (z == 1) ? Wk : (z == 2) ? Wv : Wo;
    unsigned short* dst = (z < 3) ? (wt + (size_t)z * 512 * 512) : woT;
    const int k0 = blockIdx.x * 32, n0 = blockIdx.y * 32;
    const int ty = tid >> 3, tx = tid & 7;

    float4 v = *(const float4*)&W[(size_t)(k0 + ty) * 512 + n0 + tx * 4];
    tile[ty][tx*4+0] = v.x; tile[ty][tx*4+1] = v.y;
    tile[ty][tx*4+2] = v.z; tile[ty][tx*4+3] = v.w;
    __syncthreads();
    ushort4 o;
    o.x = f2bf(tile[tx*4+0][ty]);
    o.y = f2bf(tile[tx*4+1][ty]);
    o.z = f2bf(tile[tx*4+2][ty]);
    o.w = f2bf(tile[tx*4+3][ty]);
    *(ushort4*)&dst[(size_t)(n0 + ty) * 512 + k0 + tx * 4] = o;
}

// ---------------------------------------------------------------------------
// K0d: transpose vbf [bh][s][64] -> vT [bh][64][s] (bf16, 4 MB)
// ---------------------------------------------------------------------------
__global__ __launch_bounds__(256) void transpose_v_kernel(
    const unsigned short* __restrict__ vbf, unsigned short* __restrict__ vT)
{
    __shared__ unsigned short t_s[64][72];
    const int tid = threadIdx.x;
    const int bh = blockIdx.y;
    const int s0 = blockIdx.x * 64;

    // load rows [s][dh] coalesced, scatter into t_s[dh][s]
    #pragma unroll
    for (int rep = 0; rep < 2; ++rep) {
        int idx = rep * 256 + tid;
        int sr = idx >> 3, cg = idx & 7;
        int4 vv = *(const int4*)&vbf[((size_t)bh * TT + s0 + sr) * 64 + cg * 8];
        const unsigned short* pv = (const unsigned short*)&vv;
        #pragma unroll
        for (int j = 0; j < 8; ++j) t_s[cg * 8 + j][sr] = pv[j];
    }
    __syncthreads();
    // write rows [dh][s] coalesced
    #pragma unroll
    for (int rep = 0; rep < 2; ++rep) {
        int idx = rep * 256 + tid;
        int dh = idx >> 3, cg = idx & 7;
        *(int4*)&vT[((size_t)bh * 64 + dh) * TT + s0 + cg * 8] =
            *(const int4*)&t_s[dh][cg * 8];
    }
}

// ---------------------------------------------------------------------------
// K1: proj GEMM via MFMA: C[4096,1544] = xbf @ wt^T.
// ---------------------------------------------------------------------------
__global__ __launch_bounds__(256) void proj_mfma_kernel(
    const unsigned short* __restrict__ xbf,   // [4096][512]
    const unsigned short* __restrict__ wt,    // [1600][512], rows 0..1543 valid
    const float* __restrict__ bq, const float* __restrict__ bk,
    const float* __restrict__ bv, const float* __restrict__ bs,
    unsigned short* __restrict__ qbf, unsigned short* __restrict__ kbf,
    unsigned short* __restrict__ vbf, float* __restrict__ sigma_out)
{
    __shared__ unsigned short a_s[64][64];
    __shared__ unsigned short b_s[64][64];
    const int tid = threadIdx.x;
    const int w = tid >> 6, l = tid & 63, lr = l & 15, lg = l >> 4;
    const int ct = blockIdx.x;          // 0..24
    const int m0 = blockIdx.y * 64;
    const int n0 = ct * 64;

    f32x4 acc[4];
    #pragma unroll
    for (int nb = 0; nb < 4; ++nb) acc[nb] = (f32x4){0.f, 0.f, 0.f, 0.f};

    for (int k0 = 0; k0 < 512; k0 += 64) {
        __syncthreads();
        #pragma unroll
        for (int rep = 0; rep < 2; ++rep) {
            int idx = rep * 256 + tid;
            int row = idx >> 3, cg = idx & 7;
            *(int4*)&a_s[row][(cg ^ (row & 7)) * 8] =
                *(const int4*)&xbf[(size_t)(m0 + row) * 512 + k0 + cg * 8];
            *(int4*)&b_s[row][(cg ^ (row & 7)) * 8] =
                *(const int4*)&wt[(size_t)(n0 + row) * 512 + k0 + cg * 8];
        }
        __syncthreads();
        #pragma unroll
        for (int ks = 0; ks < 2; ++ks) {
            int arow = w * 16 + lr;
            bf8_t af = *(const bf8_t*)&a_s[arow][((ks*4 + lg) ^ (arow & 7)) * 8];
            #pragma unroll
            for (int nb = 0; nb < 4; ++nb) {
                int brow = nb * 16 + lr;
                bf8_t bf = *(const bf8_t*)&b_s[brow][((ks*4 + lg) ^ (brow & 7)) * 8];
                acc[nb] = __builtin_amdgcn_mfma_f32_16x16x32_bf16(af, bf, acc[nb], 0, 0, 0);
            }
        }
    }

    if (ct < 24) {
        const int seg = ct >> 3;
        const int h = ct & 7;
        const float* bias = (seg == 0) ? bq : (seg == 1) ? bk : bv;
        unsigned short* dst = (seg == 0) ? qbf : (seg == 1) ? kbf : vbf;
        const float sc = (seg == 0) ? 0.125f : 1.f;
        #pragma unroll
        for (int nb = 0; nb < 4; ++nb) {
            float bb = bias[h * 64 + nb * 16 + lr];
            #pragma unroll
            for (int r = 0; r < 4; ++r) {
                int m = m0 + w * 16 + lg * 4 + r;
                int b = m >> 10, t = m & 1023;
                dst[((size_t)((b*HH + h)*TT + t)) * 64 + nb * 16 + lr] =
                    f2bf((acc[nb][r] + bb) * sc);
            }
        }
    } else if (lr < 8) {
        float bb = bs[lr];
        #pragma unroll
        for (int r = 0; r < 4; ++r) {
            int m = m0 + w * 16 + lg * 4 + r;
            int b = m >> 10, t = m & 1023;
            sigma_out[(size_t)(b*HH + lr)*TT + t] = softplus_f(acc[0][r] + bb) + 1e-6f;
        }
    }
}

// ---------------------------------------------------------------------------
// K2: barrier-free fused attention + prior.
// K and V^T fragments loaded directly from global (L2-resident, 4 MB each);
// only wave-private p_lds round-trip for the P re-layout. No __syncthreads.
// Prior computed post-loop with per-lane-contiguous columns -> float4 stores.
// ---------------------------------------------------------------------------
__global__ __launch_bounds__(256) void attn_kernel(
    const unsigned short* __restrict__ qbf,
    const unsigned short* __restrict__ kbf,
    const unsigned short* __restrict__ vT,
    const float* __restrict__ sigma,
    float* __restrict__ series, float* __restrict__ prior,
    unsigned short* __restrict__ obf)
{
    __shared__ unsigned short p_lds[4][16][72];   // per-wave P tile [qrow][s]

    const int tid = threadIdx.x;
    const int w  = tid >> 6, l = tid & 63;
    const int lr = l & 15,  lg = l >> 4;
    const int bh = blockIdx.y;
    const int qr = blockIdx.x * 64 + w * 16;

    const unsigned short* kb = kbf + (size_t)bh * TT * 64;   // [s][dh]
    const unsigned short* vb = vT  + (size_t)bh * 64 * TT;   // [dh][s]

    bf8_t aq[2];
    {
        const unsigned short* qrow = &qbf[((size_t)bh * TT + qr + lr) * 64];
        aq[0] = *(const bf8_t*)&qrow[lg * 8];
        aq[1] = *(const bf8_t*)&qrow[32 + lg * 8];
    }

    // ---------------- sweep 1: row sums ----------------
    float psum[4] = {0.f, 0.f, 0.f, 0.f};
    for (int st = 0; st < 16; ++st) {
        #pragma unroll
        for (int nb = 0; nb < 4; ++nb) {
            f32x4 acc = {0.f, 0.f, 0.f, 0.f};
            #pragma unroll
            for (int c = 0; c < 2; ++c) {
                bf8_t bk = *(const bf8_t*)&kb[(size_t)(st*64 + nb*16 + lr)*64 + c*32 + lg*8];
                acc = __builtin_amdgcn_mfma_f32_16x16x32_bf16(aq[c], bk, acc, 0, 0, 0);
            }
            #pragma unroll
            for (int r = 0; r < 4; ++r) psum[r] += __expf(acc[r]);
        }
    }
    #pragma unroll
    for (int r = 0; r < 4; ++r) {
        psum[r] += __shfl_xor(psum[r], 1);
        psum[r] += __shfl_xor(psum[r], 2);
        psum[r] += __shfl_xor(psum[r], 4);
        psum[r] += __shfl_xor(psum[r], 8);
    }
    float inv[4];
    #pragma unroll
    for (int r = 0; r < 4; ++r) inv[r] = 1.f / psum[r];

    // ---------------- sweep 2: series + PV ----------------
    f32x4 oacc[4];
    #pragma unroll
    for (int nb = 0; nb < 4; ++nb) oacc[nb] = (f32x4){0.f, 0.f, 0.f, 0.f};

    for (int st = 0; st < 16; ++st) {
        #pragma unroll
        for (int nb = 0; nb < 4; ++nb) {
            f32x4 acc = {0.f, 0.f, 0.f, 0.f};
            #pragma unroll
            for (int c = 0; c < 2; ++c) {
                bf8_t bk = *(const bf8_t*)&kb[(size_t)(st*64 + nb*16 + lr)*64 + c*32 + lg*8];
                acc = __builtin_amdgcn_mfma_f32_16x16x32_bf16(aq[c], bk, acc, 0, 0, 0);
            }
            #pragma unroll
            for (int r = 0; r < 4; ++r) {
                float e = __expf(acc[r]);
                series[((size_t)bh * TT + qr + lg * 4 + r) * TT + st * 64 + nb * 16 + lr]
                    = e * inv[r];
                p_lds[w][lg * 4 + r][nb * 16 + lr] = f2bf(e);
            }
        }

        bf8_t pa0 = *(const bf8_t*)&p_lds[w][lr][lg * 8];
        bf8_t pa1 = *(const bf8_t*)&p_lds[w][lr][32 + lg * 8];
        #pragma unroll
        for (int nb = 0; nb < 4; ++nb) {
            #pragma unroll
            for (int c = 0; c < 2; ++c) {
                bf8_t bv = *(const bf8_t*)&vb[(size_t)(nb*16 + lr)*TT + st*64 + c*32 + lg*8];
                oacc[nb] = __builtin_amdgcn_mfma_f32_16x16x32_bf16(
                    (c == 0) ? pa0 : pa1, bv, oacc[nb], 0, 0, 0);
            }
        }
    }

    const int b = bh >> 3, h = bh & 7;
    #pragma unroll
    for (int nb = 0; nb < 4; ++nb)
        #pragma unroll
        for (int r = 0; r < 4; ++r) {
            int t = qr + lg * 4 + r;
            obf[((size_t)(b * TT + t)) * 512 + h * 64 + nb * 16 + lr] =
                f2bf(oacc[nb][r] * inv[r]);
        }

    // ---------------- prior: wave's 16 rows, lane owns 16 contiguous cols ----
    for (int rr = 0; rr < 16; ++rr) {
        int t = qr + rr;
        float sg = sigma[(size_t)bh * TT + t];
        float cc = 1.f / (2.f * (sg * sg + 1e-6f));
        float e[16]; float sum = 0.f;
        #pragma unroll
        for (int j = 0; j < 16; ++j) {
            float d = (float)(t - (l * 16 + j));
            e[j] = __expf(-(d * d) * cc);
            sum += e[j];
        }
        sum += __shfl_xor(sum, 32);
        sum += __shfl_xor(sum, 16);
        sum += __shfl_xor(sum, 8);
        sum += __shfl_xor(sum, 4);
        sum += __shfl_xor(sum, 2);
        sum += __shfl_xor(sum, 1);
        float pinv = 1.f / (sum + 1e-9f);
        float* pr = prior + ((size_t)bh * TT + t) * TT + l * 16;
        #pragma unroll
        for (int g = 0; g < 4; ++g) {
            float4 o;
            o.x = e[g*4+0] * pinv; o.y = e[g*4+1] * pinv;
            o.z = e[g*4+2] * pinv; o.w = e[g*4+3] * pinv;
            *(float4*)&pr[g * 4] = o;
        }
    }
}

// ---------------------------------------------------------------------------
// K3: out = obf[4096,512] @ woT^T + bo (MFMA), f32 out.
// ---------------------------------------------------------------------------
__global__ __launch_bounds__(256) void outproj_mfma_kernel(
    const unsigned short* __restrict__ obf,   // [4096][512]
    const unsigned short* __restrict__ woT,   // [512][512]
    const float* __restrict__ bo, float* __restrict__ out)
{
    __shared__ unsigned short a_s[64][64];
    __shared__ unsigned short b_s[64][64];
    const int tid = threadIdx.x;
    const int w = tid >> 6, l = tid & 63, lr = l & 15, lg = l >> 4;
    const int n0 = blockIdx.x * 64;
    const int m0 = blockIdx.y * 64;

    f32x4 acc[4];
    #pragma unroll
    for (int nb = 0; nb < 4; ++nb) acc[nb] = (f32x4){0.f, 0.f, 0.f, 0.f};

    for (int k0 = 0; k0 < 512; k0 += 64) {
        __syncthreads();
        #pragma unroll
        for (int rep = 0; rep < 2; ++rep) {
            int idx = rep * 256 + tid;
            int row = idx >> 3, cg = idx & 7;
            *(int4*)&a_s[row][(cg ^ (row & 7)) * 8] =
                *(const int4*)&obf[(size_t)(m0 + row) * 512 + k0 + cg * 8];
            *(int4*)&b_s[row][(cg ^ (row & 7)) * 8] =
                *(const int4*)&woT[(size_t)(n0 + row) * 512 + k0 + cg * 8];
        }
        __syncthreads();
        #pragma unroll
        for (int ks = 0; ks < 2; ++ks) {
            int arow = w * 16 + lr;
            bf8_t af = *(const bf8_t*)&a_s[arow][((ks*4 + lg) ^ (arow & 7)) * 8];
            #pragma unroll
            for (int nb = 0; nb < 4; ++nb) {
                int brow = nb * 16 + lr;
                bf8_t bf = *(const bf8_t*)&b_s[brow][((ks*4 + lg) ^ (brow & 7)) * 8];
                acc[nb] = __builtin_amdgcn_mfma_f32_16x16x32_bf16(af, bf, acc[nb], 0, 0, 0);
            }
        }
    }

    #pragma unroll
    for (int nb = 0; nb < 4; ++nb) {
        float bb = bo[n0 + nb * 16 + lr];
        #pragma unroll
        for (int r = 0; r < 4; ++r) {
            int m = m0 + w * 16 + lg * 4 + r;
            out[(size_t)m * 512 + n0 + nb * 16 + lr] = acc[nb][r] + bb;
        }
    }
}

// ---------------------------------------------------------------------------
extern "C" void kernel_launch(void* const* d_in, const int* in_sizes, int n_in,
                              void* d_out, int out_size, void* d_ws, size_t ws_size,
                              hipStream_t stream)
{
    const float* x    = (const float*)d_in[0];
    const float* Wq_w = (const float*)d_in[1];
    const float* Wq_b = (const float*)d_in[2];
    const float* Wk_w = (const float*)d_in[3];
    const float* Wk_b = (const float*)d_in[4];
    const float* Wv_w = (const float*)d_in[5];
    const float* Wv_b = (const float*)d_in[6];
    const float* Ws_w = (const float*)d_in[7];
    const float* Ws_b = (const float*)d_in[8];
    const float* Wo_w = (const float*)d_in[9];
    const float* Wo_b = (const float*)d_in[10];

    float* out    = (float*)d_out;                      // [B,T,D]
    float* series = out + (size_t)BB*TT*DD;             // [B,H,T,T]
    float* prior  = series + (size_t)BB*HH*TT*TT;       // [B,H,T,T]
    float* sigma  = prior + (size_t)BB*HH*TT*TT;        // [B,H,T]

    const size_t nx = (size_t)BB*TT*DD;                 // 2,097,152
    unsigned short* xbf = (unsigned short*)d_ws;        // [4096][512]
    unsigned short* wt  = xbf + nx;                     // [1600][512]
    unsigned short* woT = wt + (size_t)1600*512;        // [512][512]
    unsigned short* qbf = woT + (size_t)512*512;        // [B,H,T,64]
    unsigned short* kbf = qbf + nx;
    unsigned short* vbf = kbf + nx;
    unsigned short* vTb = vbf + nx;                     // [B,H,64,T]
    unsigned short* obf = vTb + nx;                     // [4096][512]

    cast_x_kernel<<<1024, 256, 0, stream>>>(x, xbf);
    transpose_w_kernel<<<dim3(16, 16, 5), 256, 0, stream>>>(
        Wq_w, Wk_w, Wv_w, Wo_w, Ws_w, wt, woT);

    proj_mfma_kernel<<<dim3(25, 64), 256, 0, stream>>>(
        xbf, wt, Wq_b, Wk_b, Wv_b, Ws_b, qbf, kbf, vbf, sigma);

    transpose_v_kernel<<<dim3(16, 32), 256, 0, stream>>>(vbf, vTb);

    attn_kernel<<<dim3(16, 32), 256, 0, stream>>>(
        qbf, kbf, vTb, sigma, series, prior, obf);

    outproj_mfma_kernel<<<dim3(8, 64), 256, 0, stream>>>(obf, woT, Wo_b, out);
}

// Round 6
// 130.843 us; speedup vs baseline: 1.4776x; 1.4776x over previous
//
#include <hip/hip_runtime.h>
#include <math.h>

#define BB 4
#define TT 1024
#define DD 512
#define HH 8
#define DHH 64

typedef short bf8_t __attribute__((ext_vector_type(8)));
typedef float f32x4 __attribute__((ext_vector_type(4)));

__device__ __forceinline__ float softplus_f(float z) {
    return fmaxf(z, 0.f) + log1pf(__expf(-fabsf(z)));
}

__device__ __forceinline__ unsigned short f2bf(float f) {
    union { float f; unsigned int u; } v; v.f = f;
    return (unsigned short)((v.u + 0x7FFFu + ((v.u >> 16) & 1u)) >> 16);
}

// ---------------------------------------------------------------------------
// K0a: cast x (f32 [4096][512]) -> bf16
// ---------------------------------------------------------------------------
__global__ __launch_bounds__(256) void cast_x_kernel(
    const float* __restrict__ x, unsigned short* __restrict__ xbf)
{
    int i = blockIdx.x * 256 + threadIdx.x;   // 8 elems per thread
    float4 a = *(const float4*)&x[(size_t)i * 8];
    float4 b = *(const float4*)&x[(size_t)i * 8 + 4];
    union { unsigned short u[8]; int4 v; } o;
    o.u[0] = f2bf(a.x); o.u[1] = f2bf(a.y); o.u[2] = f2bf(a.z); o.u[3] = f2bf(a.w);
    o.u[4] = f2bf(b.x); o.u[5] = f2bf(b.y); o.u[6] = f2bf(b.z); o.u[7] = f2bf(b.w);
    *(int4*)&xbf[(size_t)i * 8] = o.v;
}

// ---------------------------------------------------------------------------
// K0b: transpose+cast the 512x512 weights into W^T bf16 [n][k].
// z: 0=Wq 1=Wk 2=Wv (-> wt rows z*512..) 3=Wo (-> woT) 4=Ws (-> wt rows 1536..)
// ---------------------------------------------------------------------------
__global__ __launch_bounds__(256) void transpose_w_kernel(
    const float* __restrict__ Wq, const float* __restrict__ Wk,
    const float* __restrict__ Wv, const float* __restrict__ Wo,
    const float* __restrict__ Ws,
    unsigned short* __restrict__ wt, unsigned short* __restrict__ woT)
{
    __shared__ float tile[32][33];
    const int tid = threadIdx.x;
    const int z = blockIdx.z;
    if (z == 4) {                       // Ws [512][8] -> wt rows 1536..1543
        if (blockIdx.x != 0 || blockIdx.y != 0) return;
        #pragma unroll
        for (int i = 0; i < 16; ++i) {
            int idx = i * 256 + tid;    // = k*8 + n
            int k = idx >> 3, n = idx & 7;
            wt[(size_t)(1536 + n) * 512 + k] = f2bf(Ws[idx]);
        }
        return;
    }
    const float* W = (z == 0) ? Wq : (z == 1) ? Wk : (z == 2) ? Wv : Wo;
    unsigned short* dst = (z < 3) ? (wt + (size_t)z * 512 * 512) : woT;
    const int k0 = blockIdx.x * 32, n0 = blockIdx.y * 32;
    const int ty = tid >> 3, tx = tid & 7;

    float4 v = *(const float4*)&W[(size_t)(k0 + ty) * 512 + n0 + tx * 4];
    tile[ty][tx*4+0] = v.x; tile[ty][tx*4+1] = v.y;
    tile[ty][tx*4+2] = v.z; tile[ty][tx*4+3] = v.w;
    __syncthreads();
    ushort4 o;
    o.x = f2bf(tile[tx*4+0][ty]);
    o.y = f2bf(tile[tx*4+1][ty]);
    o.z = f2bf(tile[tx*4+2][ty]);
    o.w = f2bf(tile[tx*4+3][ty]);
    *(ushort4*)&dst[(size_t)(n0 + ty) * 512 + k0 + tx * 4] = o;
}

// ---------------------------------------------------------------------------
// K1: proj GEMM via MFMA: C[4096,1544] = xbf @ wt^T.
// ---------------------------------------------------------------------------
__global__ __launch_bounds__(256) void proj_mfma_kernel(
    const unsigned short* __restrict__ xbf,   // [4096][512]
    const unsigned short* __restrict__ wt,    // [1600][512], rows 0..1543 valid
    const float* __restrict__ bq, const float* __restrict__ bk,
    const float* __restrict__ bv, const float* __restrict__ bs,
    unsigned short* __restrict__ qbf, unsigned short* __restrict__ kbf,
    unsigned short* __restrict__ vbf, float* __restrict__ sigma_out)
{
    __shared__ unsigned short a_s[64][64];
    __shared__ unsigned short b_s[64][64];
    const int tid = threadIdx.x;
    const int w = tid >> 6, l = tid & 63, lr = l & 15, lg = l >> 4;
    const int ct = blockIdx.x;          // 0..24
    const int m0 = blockIdx.y * 64;
    const int n0 = ct * 64;

    f32x4 acc[4];
    #pragma unroll
    for (int nb = 0; nb < 4; ++nb) acc[nb] = (f32x4){0.f, 0.f, 0.f, 0.f};

    for (int k0 = 0; k0 < 512; k0 += 64) {
        __syncthreads();
        #pragma unroll
        for (int rep = 0; rep < 2; ++rep) {
            int idx = rep * 256 + tid;
            int row = idx >> 3, cg = idx & 7;
            *(int4*)&a_s[row][(cg ^ (row & 7)) * 8] =
                *(const int4*)&xbf[(size_t)(m0 + row) * 512 + k0 + cg * 8];
            *(int4*)&b_s[row][(cg ^ (row & 7)) * 8] =
                *(const int4*)&wt[(size_t)(n0 + row) * 512 + k0 + cg * 8];
        }
        __syncthreads();
        #pragma unroll
        for (int ks = 0; ks < 2; ++ks) {
            int arow = w * 16 + lr;
            bf8_t af = *(const bf8_t*)&a_s[arow][((ks*4 + lg) ^ (arow & 7)) * 8];
            #pragma unroll
            for (int nb = 0; nb < 4; ++nb) {
                int brow = nb * 16 + lr;
                bf8_t bf = *(const bf8_t*)&b_s[brow][((ks*4 + lg) ^ (brow & 7)) * 8];
                acc[nb] = __builtin_amdgcn_mfma_f32_16x16x32_bf16(af, bf, acc[nb], 0, 0, 0);
            }
        }
    }

    if (ct < 24) {
        const int seg = ct >> 3;
        const int h = ct & 7;
        const float* bias = (seg == 0) ? bq : (seg == 1) ? bk : bv;
        unsigned short* dst = (seg == 0) ? qbf : (seg == 1) ? kbf : vbf;
        const float sc = (seg == 0) ? 0.125f : 1.f;
        #pragma unroll
        for (int nb = 0; nb < 4; ++nb) {
            float bb = bias[h * 64 + nb * 16 + lr];
            #pragma unroll
            for (int r = 0; r < 4; ++r) {
                int m = m0 + w * 16 + lg * 4 + r;
                int b = m >> 10, t = m & 1023;
                dst[((size_t)((b*HH + h)*TT + t)) * 64 + nb * 16 + lr] =
                    f2bf((acc[nb][r] + bb) * sc);
            }
        }
    } else if (lr < 8) {
        float bb = bs[lr];
        #pragma unroll
        for (int r = 0; r < 4; ++r) {
            int m = m0 + w * 16 + lg * 4 + r;
            int b = m >> 10, t = m & 1023;
            sigma_out[(size_t)(b*HH + lr)*TT + t] = softplus_f(acc[0][r] + bb) + 1e-6f;
        }
    }
}

// ---------------------------------------------------------------------------
// K2: fused attention + prior (LDS-staged, 128-row K/V chunks -> half the
// barriers). series = softmax(QK^T/8); obf = series @ V (bf16 [b,t,h*64+dh]);
// prior written post-loop with contiguous float4 stores.
// ---------------------------------------------------------------------------
__global__ __launch_bounds__(256) void attn_kernel(
    const unsigned short* __restrict__ qbf,
    const unsigned short* __restrict__ kbf,
    const unsigned short* __restrict__ vbf,
    const float* __restrict__ sigma,
    float* __restrict__ series, float* __restrict__ prior,
    unsigned short* __restrict__ obf)
{
    __shared__ unsigned short k_lds[2][64][72];   // K chunk halves [s][dh]
    __shared__ unsigned short v_lds[2][64][64];   // V^T chunk halves [dh][s], swizzled
    __shared__ unsigned short p_lds[4][16][72];   // per-wave P tile [qrow][s]

    const int tid = threadIdx.x;
    const int w  = tid >> 6, l = tid & 63;
    const int lr = l & 15,  lg = l >> 4;
    const int bh = blockIdx.y;
    const int qr = blockIdx.x * 64 + w * 16;

    bf8_t aq[2];
    {
        const unsigned short* qrow = &qbf[((size_t)bh * TT + qr + lr) * 64];
        aq[0] = *(const bf8_t*)&qrow[lg * 8];
        aq[1] = *(const bf8_t*)&qrow[32 + lg * 8];
    }

    // ---------------- sweep 1: row sums ----------------
    float psum[4] = {0.f, 0.f, 0.f, 0.f};
    for (int st2 = 0; st2 < 8; ++st2) {
        __syncthreads();
        #pragma unroll
        for (int rep = 0; rep < 4; ++rep) {
            int idx = rep * 256 + tid;
            int row = idx >> 3, cg = idx & 7;       // row 0..127
            *(int4*)&k_lds[row >> 6][row & 63][cg * 8] =
                *(const int4*)&kbf[((size_t)bh * TT + st2 * 128 + row) * 64 + cg * 8];
        }
        __syncthreads();
        #pragma unroll
        for (int sub = 0; sub < 2; ++sub) {
            #pragma unroll
            for (int nb = 0; nb < 4; ++nb) {
                f32x4 acc = {0.f, 0.f, 0.f, 0.f};
                #pragma unroll
                for (int c = 0; c < 2; ++c) {
                    bf8_t bk = *(const bf8_t*)&k_lds[sub][nb * 16 + lr][c * 32 + lg * 8];
                    acc = __builtin_amdgcn_mfma_f32_16x16x32_bf16(aq[c], bk, acc, 0, 0, 0);
                }
                #pragma unroll
                for (int r = 0; r < 4; ++r) psum[r] += __expf(acc[r]);
            }
        }
    }
    #pragma unroll
    for (int r = 0; r < 4; ++r) {
        psum[r] += __shfl_xor(psum[r], 1);
        psum[r] += __shfl_xor(psum[r], 2);
        psum[r] += __shfl_xor(psum[r], 4);
        psum[r] += __shfl_xor(psum[r], 8);
    }
    float inv[4];
    #pragma unroll
    for (int r = 0; r < 4; ++r) inv[r] = 1.f / psum[r];

    // ---------------- sweep 2: series + PV ----------------
    f32x4 oacc[4];
    #pragma unroll
    for (int nb = 0; nb < 4; ++nb) oacc[nb] = (f32x4){0.f, 0.f, 0.f, 0.f};

    for (int st2 = 0; st2 < 8; ++st2) {
        __syncthreads();
        #pragma unroll
        for (int rep = 0; rep < 4; ++rep) {
            int idx = rep * 256 + tid;
            int row = idx >> 3, cg = idx & 7;       // row 0..127
            *(int4*)&k_lds[row >> 6][row & 63][cg * 8] =
                *(const int4*)&kbf[((size_t)bh * TT + st2 * 128 + row) * 64 + cg * 8];
        }
        #pragma unroll
        for (int rep = 0; rep < 4; ++rep) {
            int idx = rep * 256 + tid;
            int sr = idx >> 3, cg = idx & 7;        // sr 0..127
            int4 vv = *(const int4*)&vbf[((size_t)bh * TT + st2 * 128 + sr) * 64 + cg * 8];
            const unsigned short* pv = (const unsigned short*)&vv;
            int half = sr >> 6, s64 = sr & 63;
            #pragma unroll
            for (int j = 0; j < 8; ++j) {
                int row = cg * 8 + j;                        // dh
                int gsw = ((s64 >> 3) ^ j ^ cg) & 7;
                v_lds[half][row][gsw * 8 + (s64 & 7)] = pv[j];
            }
        }
        __syncthreads();

        #pragma unroll
        for (int sub = 0; sub < 2; ++sub) {
            const int st = st2 * 2 + sub;
            #pragma unroll
            for (int nb = 0; nb < 4; ++nb) {
                f32x4 acc = {0.f, 0.f, 0.f, 0.f};
                #pragma unroll
                for (int c = 0; c < 2; ++c) {
                    bf8_t bk = *(const bf8_t*)&k_lds[sub][nb * 16 + lr][c * 32 + lg * 8];
                    acc = __builtin_amdgcn_mfma_f32_16x16x32_bf16(aq[c], bk, acc, 0, 0, 0);
                }
                #pragma unroll
                for (int r = 0; r < 4; ++r) {
                    float e = __expf(acc[r]);
                    series[((size_t)bh * TT + qr + lg * 4 + r) * TT + st * 64 + nb * 16 + lr]
                        = e * inv[r];
                    p_lds[w][lg * 4 + r][nb * 16 + lr] = f2bf(e);
                }
            }

            bf8_t pa0 = *(const bf8_t*)&p_lds[w][lr][lg * 8];
            bf8_t pa1 = *(const bf8_t*)&p_lds[w][lr][32 + lg * 8];
            #pragma unroll
            for (int nb = 0; nb < 4; ++nb) {
                #pragma unroll
                for (int c = 0; c < 2; ++c) {
                    int row = nb * 16 + lr;
                    int gsw = ((c * 4 + lg) ^ (row & 7) ^ (row >> 3)) & 7;
                    bf8_t bv = *(const bf8_t*)&v_lds[sub][row][gsw * 8];
                    oacc[nb] = __builtin_amdgcn_mfma_f32_16x16x32_bf16(
                        (c == 0) ? pa0 : pa1, bv, oacc[nb], 0, 0, 0);
                }
            }
        }
    }

    const int b = bh >> 3, h = bh & 7;
    #pragma unroll
    for (int nb = 0; nb < 4; ++nb)
        #pragma unroll
        for (int r = 0; r < 4; ++r) {
            int t = qr + lg * 4 + r;
            obf[((size_t)(b * TT + t)) * 512 + h * 64 + nb * 16 + lr] =
                f2bf(oacc[nb][r] * inv[r]);
        }

    // ---------------- prior: wave's 16 rows, lane owns 16 contiguous cols ----
    for (int rr = 0; rr < 16; ++rr) {
        int t = qr + rr;
        float sg = sigma[(size_t)bh * TT + t];
        float cc = 1.f / (2.f * (sg * sg + 1e-6f));
        float e[16]; float sum = 0.f;
        #pragma unroll
        for (int j = 0; j < 16; ++j) {
            float d = (float)(t - (l * 16 + j));
            e[j] = __expf(-(d * d) * cc);
            sum += e[j];
        }
        sum += __shfl_xor(sum, 32);
        sum += __shfl_xor(sum, 16);
        sum += __shfl_xor(sum, 8);
        sum += __shfl_xor(sum, 4);
        sum += __shfl_xor(sum, 2);
        sum += __shfl_xor(sum, 1);
        float pinv = 1.f / (sum + 1e-9f);
        float* pr = prior + ((size_t)bh * TT + t) * TT + l * 16;
        #pragma unroll
        for (int g = 0; g < 4; ++g) {
            float4 o;
            o.x = e[g*4+0] * pinv; o.y = e[g*4+1] * pinv;
            o.z = e[g*4+2] * pinv; o.w = e[g*4+3] * pinv;
            *(float4*)&pr[g * 4] = o;
        }
    }
}

// ---------------------------------------------------------------------------
// K3: out = obf[4096,512] @ woT^T + bo (MFMA), f32 out.
// ---------------------------------------------------------------------------
__global__ __launch_bounds__(256) void outproj_mfma_kernel(
    const unsigned short* __restrict__ obf,   // [4096][512]
    const unsigned short* __restrict__ woT,   // [512][512]
    const float* __restrict__ bo, float* __restrict__ out)
{
    __shared__ unsigned short a_s[64][64];
    __shared__ unsigned short b_s[64][64];
    const int tid = threadIdx.x;
    const int w = tid >> 6, l = tid & 63, lr = l & 15, lg = l >> 4;
    const int n0 = blockIdx.x * 64;
    const int m0 = blockIdx.y * 64;

    f32x4 acc[4];
    #pragma unroll
    for (int nb = 0; nb < 4; ++nb) acc[nb] = (f32x4){0.f, 0.f, 0.f, 0.f};

    for (int k0 = 0; k0 < 512; k0 += 64) {
        __syncthreads();
        #pragma unroll
        for (int rep = 0; rep < 2; ++rep) {
            int idx = rep * 256 + tid;
            int row = idx >> 3, cg = idx & 7;
            *(int4*)&a_s[row][(cg ^ (row & 7)) * 8] =
                *(const int4*)&obf[(size_t)(m0 + row) * 512 + k0 + cg * 8];
            *(int4*)&b_s[row][(cg ^ (row & 7)) * 8] =
                *(const int4*)&woT[(size_t)(n0 + row) * 512 + k0 + cg * 8];
        }
        __syncthreads();
        #pragma unroll
        for (int ks = 0; ks < 2; ++ks) {
            int arow = w * 16 + lr;
            bf8_t af = *(const bf8_t*)&a_s[arow][((ks*4 + lg) ^ (arow & 7)) * 8];
            #pragma unroll
            for (int nb = 0; nb < 4; ++nb) {
                int brow = nb * 16 + lr;
                bf8_t bf = *(const bf8_t*)&b_s[brow][((ks*4 + lg) ^ (brow & 7)) * 8];
                acc[nb] = __builtin_amdgcn_mfma_f32_16x16x32_bf16(af, bf, acc[nb], 0, 0, 0);
            }
        }
    }

    #pragma unroll
    for (int nb = 0; nb < 4; ++nb) {
        float bb = bo[n0 + nb * 16 + lr];
        #pragma unroll
        for (int r = 0; r < 4; ++r) {
            int m = m0 + w * 16 + lg * 4 + r;
            out[(size_t)m * 512 + n0 + nb * 16 + lr] = acc[nb][r] + bb;
        }
    }
}

// ---------------------------------------------------------------------------
extern "C" void kernel_launch(void* const* d_in, const int* in_sizes, int n_in,
                              void* d_out, int out_size, void* d_ws, size_t ws_size,
                              hipStream_t stream)
{
    const float* x    = (const float*)d_in[0];
    const float* Wq_w = (const float*)d_in[1];
    const float* Wq_b = (const float*)d_in[2];
    const float* Wk_w = (const float*)d_in[3];
    const float* Wk_b = (const float*)d_in[4];
    const float* Wv_w = (const float*)d_in[5];
    const float* Wv_b = (const float*)d_in[6];
    const float* Ws_w = (const float*)d_in[7];
    const float* Ws_b = (const float*)d_in[8];
    const float* Wo_w = (const float*)d_in[9];
    const float* Wo_b = (const float*)d_in[10];

    float* out    = (float*)d_out;                      // [B,T,D]
    float* series = out + (size_t)BB*TT*DD;             // [B,H,T,T]
    float* prior  = series + (size_t)BB*HH*TT*TT;       // [B,H,T,T]
    float* sigma  = prior + (size_t)BB*HH*TT*TT;        // [B,H,T]

    const size_t nx = (size_t)BB*TT*DD;                 // 2,097,152
    unsigned short* xbf = (unsigned short*)d_ws;        // [4096][512]
    unsigned short* wt  = xbf + nx;                     // [1600][512]
    unsigned short* woT = wt + (size_t)1600*512;        // [512][512]
    unsigned short* qbf = woT + (size_t)512*512;        // [B,H,T,64]
    unsigned short* kbf = qbf + nx;
    unsigned short* vbf = kbf + nx;
    unsigned short* obf = vbf + nx;                     // [4096][512]

    cast_x_kernel<<<1024, 256, 0, stream>>>(x, xbf);
    transpose_w_kernel<<<dim3(16, 16, 5), 256, 0, stream>>>(
        Wq_w, Wk_w, Wv_w, Wo_w, Ws_w, wt, woT);

    proj_mfma_kernel<<<dim3(25, 64), 256, 0, stream>>>(
        xbf, wt, Wq_b, Wk_b, Wv_b, Ws_b, qbf, kbf, vbf, sigma);

    attn_kernel<<<dim3(16, 32), 256, 0, stream>>>(
        qbf, kbf, vbf, sigma, series, prior, obf);

    outproj_mfma_kernel<<<dim3(8, 64), 256, 0, stream>>>(obf, woT, Wo_b, out);
}

// Round 7
// 105.431 us; speedup vs baseline: 1.8337x; 1.2410x over previous
//
#include <hip/hip_runtime.h>
#include <math.h>

#define BB 4
#define TT 1024
#define DD 512
#define HH 8
#define DHH 64

typedef short bf8_t __attribute__((ext_vector_type(8)));
typedef float f32x4 __attribute__((ext_vector_type(4)));

__device__ __forceinline__ float softplus_f(float z) {
    return fmaxf(z, 0.f) + log1pf(__expf(-fabsf(z)));
}

__device__ __forceinline__ unsigned short f2bf(float f) {
    union { float f; unsigned int u; } v; v.f = f;
    return (unsigned short)((v.u + 0x7FFFu + ((v.u >> 16) & 1u)) >> 16);
}

// Raw barrier: LDS visibility only — does NOT drain vmcnt (global store acks
// stay in flight across it). Correct here because nothing re-reads the
// global stores in-kernel; LDS deps are covered by lgkmcnt(0).
__device__ __forceinline__ void bar_lgkm() {
    asm volatile("s_waitcnt lgkmcnt(0)" ::: "memory");
    __builtin_amdgcn_s_barrier();
}

// ---------------------------------------------------------------------------
// K0a: cast x (f32 [4096][512]) -> bf16
// ---------------------------------------------------------------------------
__global__ __launch_bounds__(256) void cast_x_kernel(
    const float* __restrict__ x, unsigned short* __restrict__ xbf)
{
    int i = blockIdx.x * 256 + threadIdx.x;   // 8 elems per thread
    float4 a = *(const float4*)&x[(size_t)i * 8];
    float4 b = *(const float4*)&x[(size_t)i * 8 + 4];
    union { unsigned short u[8]; int4 v; } o;
    o.u[0] = f2bf(a.x); o.u[1] = f2bf(a.y); o.u[2] = f2bf(a.z); o.u[3] = f2bf(a.w);
    o.u[4] = f2bf(b.x); o.u[5] = f2bf(b.y); o.u[6] = f2bf(b.z); o.u[7] = f2bf(b.w);
    *(int4*)&xbf[(size_t)i * 8] = o.v;
}

// ---------------------------------------------------------------------------
// K0b: transpose+cast the 512x512 weights into W^T bf16 [n][k].
// z: 0=Wq 1=Wk 2=Wv (-> wt rows z*512..) 3=Wo (-> woT) 4=Ws (-> wt rows 1536..)
// ---------------------------------------------------------------------------
__global__ __launch_bounds__(256) void transpose_w_kernel(
    const float* __restrict__ Wq, const float* __restrict__ Wk,
    const float* __restrict__ Wv, const float* __restrict__ Wo,
    const float* __restrict__ Ws,
    unsigned short* __restrict__ wt, unsigned short* __restrict__ woT)
{
    __shared__ float tile[32][33];
    const int tid = threadIdx.x;
    const int z = blockIdx.z;
    if (z == 4) {                       // Ws [512][8] -> wt rows 1536..1543
        if (blockIdx.x != 0 || blockIdx.y != 0) return;
        #pragma unroll
        for (int i = 0; i < 16; ++i) {
            int idx = i * 256 + tid;    // = k*8 + n
            int k = idx >> 3, n = idx & 7;
            wt[(size_t)(1536 + n) * 512 + k] = f2bf(Ws[idx]);
        }
        return;
    }
    const float* W = (z == 0) ? Wq : (z == 1) ? Wk : (z == 2) ? Wv : Wo;
    unsigned short* dst = (z < 3) ? (wt + (size_t)z * 512 * 512) : woT;
    const int k0 = blockIdx.x * 32, n0 = blockIdx.y * 32;
    const int ty = tid >> 3, tx = tid & 7;

    float4 v = *(const float4*)&W[(size_t)(k0 + ty) * 512 + n0 + tx * 4];
    tile[ty][tx*4+0] = v.x; tile[ty][tx*4+1] = v.y;
    tile[ty][tx*4+2] = v.z; tile[ty][tx*4+3] = v.w;
    __syncthreads();
    ushort4 o;
    o.x = f2bf(tile[tx*4+0][ty]);
    o.y = f2bf(tile[tx*4+1][ty]);
    o.z = f2bf(tile[tx*4+2][ty]);
    o.w = f2bf(tile[tx*4+3][ty]);
    *(ushort4*)&dst[(size_t)(n0 + ty) * 512 + k0 + tx * 4] = o;
}

// ---------------------------------------------------------------------------
// K1: proj GEMM via MFMA: C[4096,1544] = xbf @ wt^T.
// ---------------------------------------------------------------------------
__global__ __launch_bounds__(256) void proj_mfma_kernel(
    const unsigned short* __restrict__ xbf,   // [4096][512]
    const unsigned short* __restrict__ wt,    // [1600][512], rows 0..1543 valid
    const float* __restrict__ bq, const float* __restrict__ bk,
    const float* __restrict__ bv, const float* __restrict__ bs,
    unsigned short* __restrict__ qbf, unsigned short* __restrict__ kbf,
    unsigned short* __restrict__ vbf, float* __restrict__ sigma_out)
{
    __shared__ unsigned short a_s[64][64];
    __shared__ unsigned short b_s[64][64];
    const int tid = threadIdx.x;
    const int w = tid >> 6, l = tid & 63, lr = l & 15, lg = l >> 4;
    const int ct = blockIdx.x;          // 0..24
    const int m0 = blockIdx.y * 64;
    const int n0 = ct * 64;

    f32x4 acc[4];
    #pragma unroll
    for (int nb = 0; nb < 4; ++nb) acc[nb] = (f32x4){0.f, 0.f, 0.f, 0.f};

    for (int k0 = 0; k0 < 512; k0 += 64) {
        __syncthreads();
        #pragma unroll
        for (int rep = 0; rep < 2; ++rep) {
            int idx = rep * 256 + tid;
            int row = idx >> 3, cg = idx & 7;
            *(int4*)&a_s[row][(cg ^ (row & 7)) * 8] =
                *(const int4*)&xbf[(size_t)(m0 + row) * 512 + k0 + cg * 8];
            *(int4*)&b_s[row][(cg ^ (row & 7)) * 8] =
                *(const int4*)&wt[(size_t)(n0 + row) * 512 + k0 + cg * 8];
        }
        __syncthreads();
        #pragma unroll
        for (int ks = 0; ks < 2; ++ks) {
            int arow = w * 16 + lr;
            bf8_t af = *(const bf8_t*)&a_s[arow][((ks*4 + lg) ^ (arow & 7)) * 8];
            #pragma unroll
            for (int nb = 0; nb < 4; ++nb) {
                int brow = nb * 16 + lr;
                bf8_t bf = *(const bf8_t*)&b_s[brow][((ks*4 + lg) ^ (brow & 7)) * 8];
                acc[nb] = __builtin_amdgcn_mfma_f32_16x16x32_bf16(af, bf, acc[nb], 0, 0, 0);
            }
        }
    }

    if (ct < 24) {
        const int seg = ct >> 3;
        const int h = ct & 7;
        const float* bias = (seg == 0) ? bq : (seg == 1) ? bk : bv;
        unsigned short* dst = (seg == 0) ? qbf : (seg == 1) ? kbf : vbf;
        const float sc = (seg == 0) ? 0.125f : 1.f;
        #pragma unroll
        for (int nb = 0; nb < 4; ++nb) {
            float bb = bias[h * 64 + nb * 16 + lr];
            #pragma unroll
            for (int r = 0; r < 4; ++r) {
                int m = m0 + w * 16 + lg * 4 + r;
                int b = m >> 10, t = m & 1023;
                dst[((size_t)((b*HH + h)*TT + t)) * 64 + nb * 16 + lr] =
                    f2bf((acc[nb][r] + bb) * sc);
            }
        }
    } else if (lr < 8) {
        float bb = bs[lr];
        #pragma unroll
        for (int r = 0; r < 4; ++r) {
            int m = m0 + w * 16 + lg * 4 + r;
            int b = m >> 10, t = m & 1023;
            sigma_out[(size_t)(b*HH + lr)*TT + t] = softplus_f(acc[0][r] + bb) + 1e-6f;
        }
    }
}

// ---------------------------------------------------------------------------
// K2: fused attention + prior. Round-4 structure (64-row K/V chunks, in-loop
// prior) with a T3/T14 schedule: double-buffered LDS, prefetch-to-regs issued
// BEFORE the phase's global stores, single lgkm-only raw barrier per phase.
// No __syncthreads -> global store acks never block.
// ---------------------------------------------------------------------------
__global__ __launch_bounds__(256) void attn_kernel(
    const unsigned short* __restrict__ qbf,
    const unsigned short* __restrict__ kbf,
    const unsigned short* __restrict__ vbf,
    const float* __restrict__ sigma,
    float* __restrict__ series, float* __restrict__ prior,
    unsigned short* __restrict__ obf)
{
    __shared__ unsigned short k_lds[2][64][72];   // K tile [s][dh], dbuf
    __shared__ unsigned short v_lds[2][64][64];   // V^T tile [dh][s] swizzled, dbuf
    __shared__ unsigned short p_lds[4][16][72];   // per-wave P tile [qrow][s]

    const int tid = threadIdx.x;
    const int w  = tid >> 6, l = tid & 63;
    const int lr = l & 15,  lg = l >> 4;
    const int bh = blockIdx.y;
    const int qr = blockIdx.x * 64 + w * 16;

    const int srow = tid >> 3, scg = tid & 7;     // staging coords (rows srow, srow+32)
    const unsigned short* kb = kbf + (size_t)bh * TT * 64;
    const unsigned short* vb = vbf + (size_t)bh * TT * 64;

    bf8_t aq[2];
    {
        const unsigned short* qrow = &qbf[((size_t)bh * TT + qr + lr) * 64];
        aq[0] = *(const bf8_t*)&qrow[lg * 8];
        aq[1] = *(const bf8_t*)&qrow[32 + lg * 8];
    }

    int4 kreg0, kreg1, vreg0, vreg1;

    // ---------------- sweep 1: row sums ----------------
    float psum[4] = {0.f, 0.f, 0.f, 0.f};
    kreg0 = *(const int4*)&kb[(size_t)srow * 64 + scg * 8];
    kreg1 = *(const int4*)&kb[(size_t)(32 + srow) * 64 + scg * 8];
    *(int4*)&k_lds[0][srow][scg * 8] = kreg0;
    *(int4*)&k_lds[0][32 + srow][scg * 8] = kreg1;
    bar_lgkm();

    for (int st = 0; st < 16; ++st) {
        const int cur = st & 1;
        if (st < 15) {
            kreg0 = *(const int4*)&kb[(size_t)((st+1)*64 + srow) * 64 + scg * 8];
            kreg1 = *(const int4*)&kb[(size_t)((st+1)*64 + 32 + srow) * 64 + scg * 8];
        }
        #pragma unroll
        for (int nb = 0; nb < 4; ++nb) {
            f32x4 acc = {0.f, 0.f, 0.f, 0.f};
            #pragma unroll
            for (int c = 0; c < 2; ++c) {
                bf8_t bk = *(const bf8_t*)&k_lds[cur][nb * 16 + lr][c * 32 + lg * 8];
                acc = __builtin_amdgcn_mfma_f32_16x16x32_bf16(aq[c], bk, acc, 0, 0, 0);
            }
            #pragma unroll
            for (int r = 0; r < 4; ++r) psum[r] += __expf(acc[r]);
        }
        if (st < 15) {
            *(int4*)&k_lds[cur ^ 1][srow][scg * 8] = kreg0;
            *(int4*)&k_lds[cur ^ 1][32 + srow][scg * 8] = kreg1;
            bar_lgkm();
        }
    }
    #pragma unroll
    for (int r = 0; r < 4; ++r) {
        psum[r] += __shfl_xor(psum[r], 1);
        psum[r] += __shfl_xor(psum[r], 2);
        psum[r] += __shfl_xor(psum[r], 4);
        psum[r] += __shfl_xor(psum[r], 8);
    }
    float inv[4];
    #pragma unroll
    for (int r = 0; r < 4; ++r) inv[r] = 1.f / psum[r];

    // ---------------- sweep 2: series + PV + in-loop prior ----------------
    f32x4 oacc[4];
    #pragma unroll
    for (int nb = 0; nb < 4; ++nb) oacc[nb] = (f32x4){0.f, 0.f, 0.f, 0.f};

    // prologue: stage tile 0 into buffer 0
    kreg0 = *(const int4*)&kb[(size_t)srow * 64 + scg * 8];
    kreg1 = *(const int4*)&kb[(size_t)(32 + srow) * 64 + scg * 8];
    vreg0 = *(const int4*)&vb[(size_t)srow * 64 + scg * 8];
    vreg1 = *(const int4*)&vb[(size_t)(32 + srow) * 64 + scg * 8];
    *(int4*)&k_lds[0][srow][scg * 8] = kreg0;
    *(int4*)&k_lds[0][32 + srow][scg * 8] = kreg1;
    {
        const unsigned short* pv0 = (const unsigned short*)&vreg0;
        const unsigned short* pv1 = (const unsigned short*)&vreg1;
        #pragma unroll
        for (int j = 0; j < 8; ++j) {
            int row = scg * 8 + j;
            int g0 = ((srow >> 3) ^ j ^ scg) & 7;
            int g1 = ((srow >> 3) ^ 4 ^ j ^ scg) & 7;   // (32+srow)>>3 = (srow>>3)^4
            v_lds[0][row][g0 * 8 + (srow & 7)] = pv0[j];
            v_lds[0][row][g1 * 8 + (srow & 7)] = pv1[j];
        }
    }
    bar_lgkm();

    for (int st = 0; st < 16; ++st) {
        const int cur = st & 1;
        // 1. prefetch next tile to regs (older than this phase's stores)
        if (st < 15) {
            kreg0 = *(const int4*)&kb[(size_t)((st+1)*64 + srow) * 64 + scg * 8];
            kreg1 = *(const int4*)&kb[(size_t)((st+1)*64 + 32 + srow) * 64 + scg * 8];
            vreg0 = *(const int4*)&vb[(size_t)((st+1)*64 + srow) * 64 + scg * 8];
            vreg1 = *(const int4*)&vb[(size_t)((st+1)*64 + 32 + srow) * 64 + scg * 8];
        }

        // 2. QK^T, exp, normalized series store, stash unnormalized e
        #pragma unroll
        for (int nb = 0; nb < 4; ++nb) {
            f32x4 acc = {0.f, 0.f, 0.f, 0.f};
            #pragma unroll
            for (int c = 0; c < 2; ++c) {
                bf8_t bk = *(const bf8_t*)&k_lds[cur][nb * 16 + lr][c * 32 + lg * 8];
                acc = __builtin_amdgcn_mfma_f32_16x16x32_bf16(aq[c], bk, acc, 0, 0, 0);
            }
            #pragma unroll
            for (int r = 0; r < 4; ++r) {
                float e = __expf(acc[r]);
                series[((size_t)bh * TT + qr + lg * 4 + r) * TT + st * 64 + nb * 16 + lr]
                    = e * inv[r];
                p_lds[w][lg * 4 + r][nb * 16 + lr] = f2bf(e);
            }
        }

        // 3. PV via MFMA from swizzled V^T
        bf8_t pa0 = *(const bf8_t*)&p_lds[w][lr][lg * 8];
        bf8_t pa1 = *(const bf8_t*)&p_lds[w][lr][32 + lg * 8];
        #pragma unroll
        for (int nb = 0; nb < 4; ++nb) {
            #pragma unroll
            for (int c = 0; c < 2; ++c) {
                int row = nb * 16 + lr;
                int gsw = ((c * 4 + lg) ^ (row & 7) ^ (row >> 3)) & 7;
                bf8_t bv = *(const bf8_t*)&v_lds[cur][row][gsw * 8];
                oacc[nb] = __builtin_amdgcn_mfma_f32_16x16x32_bf16(
                    (c == 0) ? pa0 : pa1, bv, oacc[nb], 0, 0, 0);
            }
        }

        // 4. prior row t = qr + st (VALU/TRANS/store fills load-latency shadow)
        {
            int t = qr + st;
            float sg = sigma[(size_t)bh * TT + t];
            float cc = 1.f / (2.f * (sg * sg + 1e-6f));
            float e[16]; float sum = 0.f;
            #pragma unroll
            for (int j = 0; j < 16; ++j) {
                float d = (float)(t - (j * 64 + l));
                e[j] = __expf(-(d * d) * cc);
                sum += e[j];
            }
            sum += __shfl_xor(sum, 32);
            sum += __shfl_xor(sum, 16);
            sum += __shfl_xor(sum, 8);
            sum += __shfl_xor(sum, 4);
            sum += __shfl_xor(sum, 2);
            sum += __shfl_xor(sum, 1);
            float pinv = 1.f / (sum + 1e-9f);
            float* pr = prior + ((size_t)bh * TT + t) * TT;
            #pragma unroll
            for (int j = 0; j < 16; ++j) pr[j * 64 + l] = e[j] * pinv;
        }

        // 5. write prefetched tile into the other buffer; lgkm-only barrier
        if (st < 15) {
            *(int4*)&k_lds[cur ^ 1][srow][scg * 8] = kreg0;
            *(int4*)&k_lds[cur ^ 1][32 + srow][scg * 8] = kreg1;
            const unsigned short* pv0 = (const unsigned short*)&vreg0;
            const unsigned short* pv1 = (const unsigned short*)&vreg1;
            #pragma unroll
            for (int j = 0; j < 8; ++j) {
                int row = scg * 8 + j;
                int g0 = ((srow >> 3) ^ j ^ scg) & 7;
                int g1 = ((srow >> 3) ^ 4 ^ j ^ scg) & 7;
                v_lds[cur ^ 1][row][g0 * 8 + (srow & 7)] = pv0[j];
                v_lds[cur ^ 1][row][g1 * 8 + (srow & 7)] = pv1[j];
            }
            bar_lgkm();
        }
    }

    const int b = bh >> 3, h = bh & 7;
    #pragma unroll
    for (int nb = 0; nb < 4; ++nb)
        #pragma unroll
        for (int r = 0; r < 4; ++r) {
            int t = qr + lg * 4 + r;
            obf[((size_t)(b * TT + t)) * 512 + h * 64 + nb * 16 + lr] =
                f2bf(oacc[nb][r] * inv[r]);
        }
}

// ---------------------------------------------------------------------------
// K3: out = obf[4096,512] @ woT^T + bo (MFMA), f32 out.
// ---------------------------------------------------------------------------
__global__ __launch_bounds__(256) void outproj_mfma_kernel(
    const unsigned short* __restrict__ obf,   // [4096][512]
    const unsigned short* __restrict__ woT,   // [512][512]
    const float* __restrict__ bo, float* __restrict__ out)
{
    __shared__ unsigned short a_s[64][64];
    __shared__ unsigned short b_s[64][64];
    const int tid = threadIdx.x;
    const int w = tid >> 6, l = tid & 63, lr = l & 15, lg = l >> 4;
    const int n0 = blockIdx.x * 64;
    const int m0 = blockIdx.y * 64;

    f32x4 acc[4];
    #pragma unroll
    for (int nb = 0; nb < 4; ++nb) acc[nb] = (f32x4){0.f, 0.f, 0.f, 0.f};

    for (int k0 = 0; k0 < 512; k0 += 64) {
        __syncthreads();
        #pragma unroll
        for (int rep = 0; rep < 2; ++rep) {
            int idx = rep * 256 + tid;
            int row = idx >> 3, cg = idx & 7;
            *(int4*)&a_s[row][(cg ^ (row & 7)) * 8] =
                *(const int4*)&obf[(size_t)(m0 + row) * 512 + k0 + cg * 8];
            *(int4*)&b_s[row][(cg ^ (row & 7)) * 8] =
                *(const int4*)&woT[(size_t)(n0 + row) * 512 + k0 + cg * 8];
        }
        __syncthreads();
        #pragma unroll
        for (int ks = 0; ks < 2; ++ks) {
            int arow = w * 16 + lr;
            bf8_t af = *(const bf8_t*)&a_s[arow][((ks*4 + lg) ^ (arow & 7)) * 8];
            #pragma unroll
            for (int nb = 0; nb < 4; ++nb) {
                int brow = nb * 16 + lr;
                bf8_t bf = *(const bf8_t*)&b_s[brow][((ks*4 + lg) ^ (brow & 7)) * 8];
                acc[nb] = __builtin_amdgcn_mfma_f32_16x16x32_bf16(af, bf, acc[nb], 0, 0, 0);
            }
        }
    }

    #pragma unroll
    for (int nb = 0; nb < 4; ++nb) {
        float bb = bo[n0 + nb * 16 + lr];
        #pragma unroll
        for (int r = 0; r < 4; ++r) {
            int m = m0 + w * 16 + lg * 4 + r;
            out[(size_t)m * 512 + n0 + nb * 16 + lr] = acc[nb][r] + bb;
        }
    }
}

// ---------------------------------------------------------------------------
extern "C" void kernel_launch(void* const* d_in, const int* in_sizes, int n_in,
                              void* d_out, int out_size, void* d_ws, size_t ws_size,
                              hipStream_t stream)
{
    const float* x    = (const float*)d_in[0];
    const float* Wq_w = (const float*)d_in[1];
    const float* Wq_b = (const float*)d_in[2];
    const float* Wk_w = (const float*)d_in[3];
    const float* Wk_b = (const float*)d_in[4];
    const float* Wv_w = (const float*)d_in[5];
    const float* Wv_b = (const float*)d_in[6];
    const float* Ws_w = (const float*)d_in[7];
    const float* Ws_b = (const float*)d_in[8];
    const float* Wo_w = (const float*)d_in[9];
    const float* Wo_b = (const float*)d_in[10];

    float* out    = (float*)d_out;                      // [B,T,D]
    float* series = out + (size_t)BB*TT*DD;             // [B,H,T,T]
    float* prior  = series + (size_t)BB*HH*TT*TT;       // [B,H,T,T]
    float* sigma  = prior + (size_t)BB*HH*TT*TT;        // [B,H,T]

    const size_t nx = (size_t)BB*TT*DD;                 // 2,097,152
    unsigned short* xbf = (unsigned short*)d_ws;        // [4096][512]
    unsigned short* wt  = xbf + nx;                     // [1600][512]
    unsigned short* woT = wt + (size_t)1600*512;        // [512][512]
    unsigned short* qbf = woT + (size_t)512*512;        // [B,H,T,64]
    unsigned short* kbf = qbf + nx;
    unsigned short* vbf = kbf + nx;
    unsigned short* obf = vbf + nx;                     // [4096][512]

    cast_x_kernel<<<1024, 256, 0, stream>>>(x, xbf);
    transpose_w_kernel<<<dim3(16, 16, 5), 256, 0, stream>>>(
        Wq_w, Wk_w, Wv_w, Wo_w, Ws_w, wt, woT);

    proj_mfma_kernel<<<dim3(25, 64), 256, 0, stream>>>(
        xbf, wt, Wq_b, Wk_b, Wv_b, Ws_b, qbf, kbf, vbf, sigma);

    attn_kernel<<<dim3(16, 32), 256, 0, stream>>>(
        qbf, kbf, vbf, sigma, series, prior, obf);

    outproj_mfma_kernel<<<dim3(8, 64), 256, 0, stream>>>(obf, woT, Wo_b, out);
}